// Round 4
// baseline (44.802 us; speedup 1.0000x reference)
//
#include <hip/hip_runtime.h>
#include <math.h>

// Geometry (fixed by the reference).
#define HS  2048   // hidden size (output columns)
#define DIN 2048   // input dim (reduction length)
#define CT  16     // columns per tile
#define NT  (HS / CT)          // 128 column tiles per matrix
#define NBLK (NT * 4)          // 512 blocks total (4 live matrices)

// ---------------------------------------------------------------------------
// Single fused kernel.
//  Phase 1 (all 512 blocks): column-split GEMV with full-K in-block
//    reduction. block b: mat = b&3 (0:w_xf*x 1:w_hf*h0 2:w_xo*x 3:w_ho*h0),
//    tile = b>>2 (16-column strip). Thread t: tx=t&3 -> float4 of 4 cols,
//    ty=t>>2 -> 64 row phases; rows ty+64k, k=0..31. float4 weight loads
//    (16 B/lane, 256 B contiguous per 16-lane group). Partials written once,
//    non-atomically, to zp[4][2048] (pure overwrite -> poison-proof).
//  Phase 2 (last block to finish, via atomicInc ticket): gates + normalize.
//    atomicInc(cnt,511) wraps for ANY initial counter value (0xAA poison,
//    zeros, leftovers): exactly one block per call sees old==510.
// Algebra: cell = f*c0 + dot(i,c); dot(i,c) is a scalar broadcast and the
// mean/std normalization cancels constant shifts, so
//   h = o * tanh((f*c0 - mean(f*c0)) / (std(f*c0, ddof=1) + 1e-5)).
// The i and c gates (w_xi, w_hi, w_xc, w_hc, b_i, b_c) are dead.
// ---------------------------------------------------------------------------
__global__ __launch_bounds__(256) void lstm_all(
        const float* __restrict__ x,    const float* __restrict__ h0,
        const float* __restrict__ w_xf, const float* __restrict__ w_hf,
        const float* __restrict__ w_xo, const float* __restrict__ w_ho,
        const float* __restrict__ b_f,  const float* __restrict__ b_o,
        const float* __restrict__ c0,   float* __restrict__ out,
        float* __restrict__ zp /* [4][HS] */, unsigned* __restrict__ cnt) {
    const int b    = blockIdx.x;
    const int t    = threadIdx.x;
    const int mat  = b & 3;
    const int tile = b >> 2;

    const float* W;
    const float* vec;
    switch (mat) {
        case 0:  W = w_xf; vec = x;  break;
        case 1:  W = w_hf; vec = h0; break;
        case 2:  W = w_xo; vec = x;  break;
        default: W = w_ho; vec = h0; break;
    }

    __shared__ float sv[DIN];        // staged x or h0 (8 KB)
    __shared__ float4 part[4][4];    // [wave][tx] cross-wave partials
    __shared__ unsigned lastFlag;

    // stage the vector (coalesced float4)
    {
        const float4* v4 = reinterpret_cast<const float4*>(vec);
        float4* s4 = reinterpret_cast<float4*>(sv);
#pragma unroll
        for (int i = 0; i < 2; ++i) s4[t + i * 256] = v4[t + i * 256];
    }
    __syncthreads();

    const int tx = t & 3;            // float4 column group within tile
    const int ty = t >> 2;           // 0..63 row phase
    const float* wp = W + (size_t)ty * HS + tile * CT + tx * 4;

    // full-K accumulation: rows ty + 64k; 16 float4 loads in flight
    // (16 KB/wave outstanding), 4 rotating accumulators.
    float4 a[4];
#pragma unroll
    for (int q = 0; q < 4; ++q) a[q] = make_float4(0.f, 0.f, 0.f, 0.f);
#pragma unroll 16
    for (int k = 0; k < 32; ++k) {
        const float  s = sv[ty + (k << 6)];
        const float4 w = *reinterpret_cast<const float4*>(wp + ((size_t)k << 17));
        a[k & 3].x = fmaf(s, w.x, a[k & 3].x);
        a[k & 3].y = fmaf(s, w.y, a[k & 3].y);
        a[k & 3].z = fmaf(s, w.z, a[k & 3].z);
        a[k & 3].w = fmaf(s, w.w, a[k & 3].w);
    }
    float4 s4;
    s4.x = (a[0].x + a[1].x) + (a[2].x + a[3].x);
    s4.y = (a[0].y + a[1].y) + (a[2].y + a[3].y);
    s4.z = (a[0].z + a[1].z) + (a[2].z + a[3].z);
    s4.w = (a[0].w + a[1].w) + (a[2].w + a[3].w);

    // in-wave reduce over the wave's 16 ty phases (lane stride 4)
#pragma unroll
    for (int m = 4; m <= 32; m <<= 1) {
        s4.x += __shfl_xor(s4.x, m);
        s4.y += __shfl_xor(s4.y, m);
        s4.z += __shfl_xor(s4.z, m);
        s4.w += __shfl_xor(s4.w, m);
    }
    if ((t & 63) < 4) part[t >> 6][t & 3] = s4;
    __syncthreads();
    if (t < 4) {
        float4 r;
        r.x = (part[0][t].x + part[1][t].x) + (part[2][t].x + part[3][t].x);
        r.y = (part[0][t].y + part[1][t].y) + (part[2][t].y + part[3][t].y);
        r.z = (part[0][t].z + part[1][t].z) + (part[2][t].z + part[3][t].z);
        r.w = (part[0][t].w + part[1][t].w) + (part[2][t].w + part[3][t].w);
        *reinterpret_cast<float4*>(zp + mat * HS + tile * CT + t * 4) = r;
    }
    __syncthreads();   // drains vmcnt: this block's zp stores are in L2

    // ---- last-block ticket (device-scope; robust to any initial cnt) ----
    if (t == 0) {
        __threadfence();                           // release: flush L2 writes
        const unsigned old = atomicInc(cnt, NBLK - 1u);
        lastFlag = (old == NBLK - 2u);             // exactly one block/call
    }
    __syncthreads();
    if (!lastFlag) return;
    __threadfence();                               // acquire: invalidate caches

    // ---- Phase 2: finalize on the surviving block ----
    const int lane = t & 63;
    const int wv   = t >> 6;
    __shared__ float red[2][4];

    float v[8], og[8];
    float lsum = 0.f;
#pragma unroll
    for (int k = 0; k < 2; ++k) {
        const int j = t * 8 + k * 4;
        const float4 zxf = *reinterpret_cast<const float4*>(zp + 0 * HS + j);
        const float4 zhf = *reinterpret_cast<const float4*>(zp + 1 * HS + j);
        const float4 zxo = *reinterpret_cast<const float4*>(zp + 2 * HS + j);
        const float4 zho = *reinterpret_cast<const float4*>(zp + 3 * HS + j);
        const float4 bf  = *reinterpret_cast<const float4*>(b_f + j);
        const float4 bo  = *reinterpret_cast<const float4*>(b_o + j);
        const float4 cv  = *reinterpret_cast<const float4*>(c0 + j);
        const float zfv[4] = {zxf.x + zhf.x + bf.x, zxf.y + zhf.y + bf.y,
                              zxf.z + zhf.z + bf.z, zxf.w + zhf.w + bf.w};
        const float zov[4] = {zxo.x + zho.x + bo.x, zxo.y + zho.y + bo.y,
                              zxo.z + zho.z + bo.z, zxo.w + zho.w + bo.w};
        const float ccv[4] = {cv.x, cv.y, cv.z, cv.w};
#pragma unroll
        for (int q = 0; q < 4; ++q) {
            const float fg = 1.f / (1.f + expf(-zfv[q]));
            const float oo = 1.f / (1.f + expf(-zov[q]));
            const float vv = fg * ccv[q];
            v[k * 4 + q]  = vv;
            og[k * 4 + q] = oo;
            lsum += vv;
        }
    }

    // block-reduce sum(v) -> mean
#pragma unroll
    for (int s = 32; s > 0; s >>= 1) lsum += __shfl_down(lsum, s);
    if (lane == 0) red[0][wv] = lsum;
    __syncthreads();
    const float mean = (red[0][0] + red[0][1] + red[0][2] + red[0][3]) * (1.f / 2048.f);

    // block-reduce sum((v-mean)^2) -> std (ddof=1)
    float lss = 0.f;
#pragma unroll
    for (int e = 0; e < 8; ++e) {
        const float d = v[e] - mean;
        lss += d * d;
    }
#pragma unroll
    for (int s = 32; s > 0; s >>= 1) lss += __shfl_down(lss, s);
    if (lane == 0) red[1][wv] = lss;
    __syncthreads();
    const float var = (red[1][0] + red[1][1] + red[1][2] + red[1][3]) * (1.f / 2047.f);
    const float inv = 1.f / (sqrtf(var) + 1e-5f);

#pragma unroll
    for (int k = 0; k < 2; ++k) {
        const int j = t * 8 + k * 4;
        float4 r;
        r.x = og[k * 4 + 0] * tanhf((v[k * 4 + 0] - mean) * inv);
        r.y = og[k * 4 + 1] * tanhf((v[k * 4 + 1] - mean) * inv);
        r.z = og[k * 4 + 2] * tanhf((v[k * 4 + 2] - mean) * inv);
        r.w = og[k * 4 + 3] * tanhf((v[k * 4 + 3] - mean) * inv);
        *reinterpret_cast<float4*>(out + j) = r;
    }
}

extern "C" void kernel_launch(void* const* d_in, const int* in_sizes, int n_in,
                              void* d_out, int out_size, void* d_ws, size_t ws_size,
                              hipStream_t stream) {
    // setup_inputs order:
    // 0:x 1:w_xi 2:w_xf 3:w_xo 4:w_xc 5:w_hi 6:w_hf 7:w_ho 8:w_hc
    // 9:b_i 10:b_f 11:b_o 12:b_c 13:h0 14:c0
    const float* x    = (const float*)d_in[0];
    const float* w_xf = (const float*)d_in[2];
    const float* w_xo = (const float*)d_in[3];
    const float* w_hf = (const float*)d_in[6];
    const float* w_ho = (const float*)d_in[7];
    const float* b_f  = (const float*)d_in[10];
    const float* b_o  = (const float*)d_in[11];
    const float* h0   = (const float*)d_in[13];
    const float* c0   = (const float*)d_in[14];
    float* out = (float*)d_out;

    float* zp     = (float*)d_ws;                 // [4][2048] fp32 partials
    unsigned* cnt = (unsigned*)(zp + 4 * HS);     // ticket counter (any init ok)

    lstm_all<<<NBLK, 256, 0, stream>>>(x, h0, w_xf, w_hf, w_xo, w_ho,
                                       b_f, b_o, c0, out, zp, cnt);
}

// Round 5
// 27.420 us; speedup vs baseline: 1.6339x; 1.6339x over previous
//
#include <hip/hip_runtime.h>
#include <math.h>

// Geometry (fixed by the reference).
#define HS    2048            // hidden size (output columns)
#define DIN   2048            // input dim (reduction length)
#define RPS   8               // rows per slab
#define NSLAB (DIN / RPS)     // 256 slabs per matrix
#define NBLK1 (4 * NSLAB)     // 1024 stage-1 blocks
#define NBLK2 64              // stage-2 blocks

// ---------------------------------------------------------------------------
// Algebra: cell = f*c0 + dot(i,c); dot(i,c) is a scalar broadcast and the
// mean/std normalization cancels constant shifts, so
//   h = o * tanh((f*c0 - mean(f*c0)) / (std(f*c0, ddof=1) + 1e-5)).
// The i and c gates (w_xi, w_hi, w_xc, w_hc, b_i, b_c) are dead.
//
// Stage 1: slab-streaming partial GEMV. Block b: mat = b>>8
// (0:w_xf*x 1:w_hf*h0 2:w_xo*x 3:w_ho*h0), slab = b&255 -> rows
// [slab*8, slab*8+8). The block streams its 64 KB slab with 16 fully
// coalesced 4 KB instructions (wave = 64 lanes x float4 = 1 KB contiguous).
// Thread t's column-quads are FIXED (t*4 and 1024+t*4), so the 8-row
// reduction lives in two float4 registers. One coalesced 8 KB store of
// partials per block. No LDS, no atomics, pure overwrite (poison-proof).
// ---------------------------------------------------------------------------
__global__ __launch_bounds__(256) void gemv_slab(
        const float* __restrict__ x,    const float* __restrict__ h0,
        const float* __restrict__ w_xf, const float* __restrict__ w_hf,
        const float* __restrict__ w_xo, const float* __restrict__ w_ho,
        float* __restrict__ zp /* [NBLK1][HS] */) {
    const int b    = blockIdx.x;
    const int t    = threadIdx.x;
    const int mat  = b >> 8;       // mats grouped: zp rows 0..511 = f, 512..1023 = o
    const int slab = b & (NSLAB - 1);

    const float* W   = (mat == 0) ? w_xf : (mat == 1) ? w_hf
                     : (mat == 2) ? w_xo : w_ho;
    const float* vec = (mat & 1) ? h0 : x;

    const int r0 = slab * RPS;
    const float* wp = W + (size_t)r0 * HS + t * 4;

    float4 a0 = make_float4(0.f, 0.f, 0.f, 0.f);
    float4 a1 = make_float4(0.f, 0.f, 0.f, 0.f);
#pragma unroll
    for (int r = 0; r < RPS; ++r) {
        const float  s  = vec[r0 + r];  // block-uniform -> scalar load
        const float4 w0 = *reinterpret_cast<const float4*>(wp + (size_t)r * HS);
        const float4 w1 = *reinterpret_cast<const float4*>(wp + (size_t)r * HS + 1024);
        a0.x = fmaf(s, w0.x, a0.x);  a0.y = fmaf(s, w0.y, a0.y);
        a0.z = fmaf(s, w0.z, a0.z);  a0.w = fmaf(s, w0.w, a0.w);
        a1.x = fmaf(s, w1.x, a1.x);  a1.y = fmaf(s, w1.y, a1.y);
        a1.z = fmaf(s, w1.z, a1.z);  a1.w = fmaf(s, w1.w, a1.w);
    }
    float4* zrow = reinterpret_cast<float4*>(zp + (size_t)b * HS);
    zrow[t]       = a0;   // cols t*4 .. t*4+3
    zrow[256 + t] = a1;   // cols 1024+t*4 ..
}

// ---------------------------------------------------------------------------
// Stage 2: reduce 512 slab-partials per (gate, column), apply sigmoid, then
// last-block ticket -> mean/std normalize -> output.
//   block bb: gate g = bb>>5 (0=f,1=o), column group cg = bb&31 (64 cols).
//   thread t: col = cg*64 + (t&63), wave w = t>>6 sums slabs [w*128, w*128+128)
//   of zp rows [g*512 .. g*512+512) (mats x/h adjacent -> one contiguous sum).
// vbuf/obuf are fully overwritten each call; cnt uses atomicInc wrap which
// selects exactly one block per call for ANY initial value (0xAA-poison ok).
// ---------------------------------------------------------------------------
__global__ __launch_bounds__(256) void reduce_fin(
        const float* __restrict__ zp,
        const float* __restrict__ b_f, const float* __restrict__ b_o,
        const float* __restrict__ c0,  float* __restrict__ out,
        float* __restrict__ vbuf, float* __restrict__ obuf,
        unsigned* __restrict__ cnt) {
    const int t  = threadIdx.x;
    const int g  = blockIdx.x >> 5;
    const int cg = blockIdx.x & 31;
    const int cl = t & 63;          // column within group
    const int w  = t >> 6;          // wave = slab quarter

    __shared__ float part[4][64];
    __shared__ unsigned lastFlag;

    // sum 128 slab-partials (stride HS), 4 rotating accumulators
    const float* p = zp + ((size_t)(g * 512 + w * 128)) * HS + cg * 64 + cl;
    float acc[4] = {0.f, 0.f, 0.f, 0.f};
#pragma unroll 16
    for (int s = 0; s < 128; ++s) {
        acc[s & 3] += p[(size_t)s * HS];
    }
    part[w][cl] = (acc[0] + acc[1]) + (acc[2] + acc[3]);
    __syncthreads();

    if (t < 64) {
        const int col = cg * 64 + t;
        const float z = (part[0][t] + part[1][t]) + (part[2][t] + part[3][t]);
        if (g == 0) {
            const float zf = z + b_f[col];
            const float fg = 1.f / (1.f + expf(-zf));
            vbuf[col] = fg * c0[col];           // v = f * c0
        } else {
            const float zo = z + b_o[col];
            obuf[col] = 1.f / (1.f + expf(-zo)); // o gate
        }
    }
    __syncthreads();

    // ---- last-block ticket (device scope; robust to any initial cnt) ----
    if (t == 0) {
        __threadfence();                          // release vbuf/obuf writes
        const unsigned old = atomicInc(cnt, NBLK2 - 1u);
        lastFlag = (old == NBLK2 - 2u);           // exactly one block per call
    }
    __syncthreads();
    if (!lastFlag) return;
    __threadfence();                              // acquire

    // ---- finalize: h = o * tanh((v - mean) / (std_ddof1 + 1e-5)) ----
    const int lane = t & 63;
    const int wv   = t >> 6;
    __shared__ float red[2][4];

    float v[8], og[8];
    float lsum = 0.f;
#pragma unroll
    for (int e = 0; e < 8; ++e) {
        const int j = t * 8 + e;
        v[e]  = vbuf[j];
        og[e] = obuf[j];
        lsum += v[e];
    }
#pragma unroll
    for (int s = 32; s > 0; s >>= 1) lsum += __shfl_down(lsum, s);
    if (lane == 0) red[0][wv] = lsum;
    __syncthreads();
    const float mean = (red[0][0] + red[0][1] + red[0][2] + red[0][3]) * (1.f / 2048.f);

    float lss = 0.f;
#pragma unroll
    for (int e = 0; e < 8; ++e) {
        const float d = v[e] - mean;
        lss += d * d;
    }
#pragma unroll
    for (int s = 32; s > 0; s >>= 1) lss += __shfl_down(lss, s);
    if (lane == 0) red[1][wv] = lss;
    __syncthreads();
    const float var = (red[1][0] + red[1][1] + red[1][2] + red[1][3]) * (1.f / 2047.f);
    const float inv = 1.f / (sqrtf(var) + 1e-5f);

#pragma unroll
    for (int e = 0; e < 8; ++e) {
        const int j = t * 8 + e;
        out[j] = og[e] * tanhf((v[e] - mean) * inv);
    }
}

extern "C" void kernel_launch(void* const* d_in, const int* in_sizes, int n_in,
                              void* d_out, int out_size, void* d_ws, size_t ws_size,
                              hipStream_t stream) {
    // setup_inputs order:
    // 0:x 1:w_xi 2:w_xf 3:w_xo 4:w_xc 5:w_hi 6:w_hf 7:w_ho 8:w_hc
    // 9:b_i 10:b_f 11:b_o 12:b_c 13:h0 14:c0
    const float* x    = (const float*)d_in[0];
    const float* w_xf = (const float*)d_in[2];
    const float* w_xo = (const float*)d_in[3];
    const float* w_hf = (const float*)d_in[6];
    const float* w_ho = (const float*)d_in[7];
    const float* b_f  = (const float*)d_in[10];
    const float* b_o  = (const float*)d_in[11];
    const float* h0   = (const float*)d_in[13];
    const float* c0   = (const float*)d_in[14];
    float* out = (float*)d_out;

    float* zp     = (float*)d_ws;            // [1024][2048] fp32 = 8 MB
    float* vbuf   = zp + (size_t)NBLK1 * HS; // 2048 fp32
    float* obuf   = vbuf + HS;               // 2048 fp32
    unsigned* cnt = (unsigned*)(obuf + HS);  // ticket (any init value ok)

    gemv_slab<<<NBLK1, 256, 0, stream>>>(x, h0, w_xf, w_hf, w_xo, w_ho, zp);
    reduce_fin<<<NBLK2, 256, 0, stream>>>(zp, b_f, b_o, c0, out, vbuf, obuf, cnt);
}

// Round 6
// 22.445 us; speedup vs baseline: 1.9961x; 1.2217x over previous
//
#include <hip/hip_runtime.h>
#include <math.h>

// Geometry (fixed by the reference).
#define HS    2048            // hidden size (output columns)
#define DIN   2048            // input dim (reduction length)
#define RPS   16              // rows per slab
#define NSLAB (DIN / RPS)     // 128 slabs per matrix
#define NBLK1 1024            // 4 mats x 128 slabs x 2 column halves
#define NBLK2 64              // stage-2 blocks

// ---------------------------------------------------------------------------
// Algebra: cell = f*c0 + dot(i,c); dot(i,c) is a scalar broadcast and the
// mean/std normalization cancels constant shifts, so
//   h = o * tanh((f*c0 - mean(f*c0)) / (std(f*c0, ddof=1) + 1e-5)).
// The i and c gates (w_xi, w_hi, w_xc, w_hc, b_i, b_c) are dead.
//
// Stage 1: slab-streaming partial GEMV. Block b: mat = b>>8, rem = b&255,
// slab = rem>>1 (16 rows), ch = rem&1 (1024-col half). The block streams a
// 16x1024 tile (64 KB) as 16 fully-coalesced 4 KB row-instructions (wave =
// 64 lanes x float4 = 1 KB contiguous). Thread t owns the FIXED col quad
// ch*1024 + t*4, so the 16-row reduction lives in registers. One coalesced
// 4 KB partial-row store per block -> zp total 4 MB. No LDS in the hot
// loop, no atomics, pure overwrite (poison-proof).
// ---------------------------------------------------------------------------
__global__ __launch_bounds__(256) void gemv_slab(
        const float* __restrict__ x,    const float* __restrict__ h0,
        const float* __restrict__ w_xf, const float* __restrict__ w_hf,
        const float* __restrict__ w_xo, const float* __restrict__ w_ho,
        float* __restrict__ zp /* [NBLK1][1024] */) {
    const int b    = blockIdx.x;
    const int t    = threadIdx.x;
    const int mat  = b >> 8;                 // 0:w_xf 1:w_hf 2:w_xo 3:w_ho
    const int rem  = b & 255;
    const int slab = rem >> 1;
    const int ch   = rem & 1;

    const float* W   = (mat == 0) ? w_xf : (mat == 1) ? w_hf
                     : (mat == 2) ? w_xo : w_ho;
    const float* vec = (mat & 1) ? h0 : x;

    const int r0 = slab * RPS;
    const float* wp = W + (size_t)r0 * HS + ch * 1024 + t * 4;

    float4 a0 = make_float4(0.f, 0.f, 0.f, 0.f);
    float4 a1 = make_float4(0.f, 0.f, 0.f, 0.f);
#pragma unroll
    for (int r = 0; r < RPS; r += 2) {
        const float  s0 = vec[r0 + r];       // block-uniform -> scalar load
        const float  s1 = vec[r0 + r + 1];
        const float4 w0 = *reinterpret_cast<const float4*>(wp + (size_t)r * HS);
        const float4 w1 = *reinterpret_cast<const float4*>(wp + (size_t)(r + 1) * HS);
        a0.x = fmaf(s0, w0.x, a0.x);  a0.y = fmaf(s0, w0.y, a0.y);
        a0.z = fmaf(s0, w0.z, a0.z);  a0.w = fmaf(s0, w0.w, a0.w);
        a1.x = fmaf(s1, w1.x, a1.x);  a1.y = fmaf(s1, w1.y, a1.y);
        a1.z = fmaf(s1, w1.z, a1.z);  a1.w = fmaf(s1, w1.w, a1.w);
    }
    float4 r4;
    r4.x = a0.x + a1.x;  r4.y = a0.y + a1.y;
    r4.z = a0.z + a1.z;  r4.w = a0.w + a1.w;
    reinterpret_cast<float4*>(zp + (size_t)b * 1024)[t] = r4;
}

// ---------------------------------------------------------------------------
// Stage 2: reduce 256 slab-partials per (gate, column) with float4 loads,
// sigmoid, then last-block ticket -> mean/std normalize -> output.
//   block bb: gate g = bb>>5, col group cg = bb&31 (64 cols).
//   thread t: fg = t&15 (float4 col quad), ph = t>>4 (16 slab phases);
//   sums slabs ph+16k (k=0..7) for both mats of the gate: 16 independent
//   float4 loads (4 x 256 B per wave-instruction, stride 8 KB; data is
//   L2/L3-resident - written by stage 1 moments earlier).
// vbuf/obuf fully overwritten each call; atomicInc-wrap ticket selects
// exactly one block per call for ANY initial counter value (0xAA poison ok).
// ---------------------------------------------------------------------------
__global__ __launch_bounds__(256) void reduce_fin(
        const float* __restrict__ zp,
        const float* __restrict__ b_f, const float* __restrict__ b_o,
        const float* __restrict__ c0,  float* __restrict__ out,
        float* __restrict__ vbuf, float* __restrict__ obuf,
        unsigned* __restrict__ cnt) {
    const int t  = threadIdx.x;
    const int g  = blockIdx.x >> 5;          // 0 = f, 1 = o
    const int cg = blockIdx.x & 31;          // 64-col group
    const int fg = t & 15;                   // float4 quad within group
    const int ph = t >> 4;                   // slab phase 0..15

    __shared__ float4 part[4][16];
    __shared__ unsigned lastFlag;

    const int ch = cg >> 4;                  // column half of this group
    const int cw = (cg & 15) * 64 + fg * 4;  // offset within the half

    float4 acc0 = make_float4(0.f, 0.f, 0.f, 0.f);
    float4 acc1 = make_float4(0.f, 0.f, 0.f, 0.f);
#pragma unroll
    for (int k = 0; k < 8; ++k) {
        const int slab = ph + (k << 4);
#pragma unroll
        for (int m = 0; m < 2; ++m) {
            const int rr = ((g * 2 + m) * NSLAB + slab) * 2 + ch;
            const float4 p = *reinterpret_cast<const float4*>(
                zp + (size_t)rr * 1024 + cw);
            float4& a = m ? acc1 : acc0;
            a.x += p.x;  a.y += p.y;  a.z += p.z;  a.w += p.w;
        }
    }
    float4 s4;
    s4.x = acc0.x + acc1.x;  s4.y = acc0.y + acc1.y;
    s4.z = acc0.z + acc1.z;  s4.w = acc0.w + acc1.w;

    // reduce the 4 in-wave phases (lanes l, l^16, l^32 hold adjacent ph)
#pragma unroll
    for (int m = 16; m <= 32; m <<= 1) {
        s4.x += __shfl_xor(s4.x, m);
        s4.y += __shfl_xor(s4.y, m);
        s4.z += __shfl_xor(s4.z, m);
        s4.w += __shfl_xor(s4.w, m);
    }
    if ((t & 63) < 16) part[t >> 6][fg] = s4;
    __syncthreads();

    if (t < 16) {
        float4 z;
        z.x = (part[0][t].x + part[1][t].x) + (part[2][t].x + part[3][t].x);
        z.y = (part[0][t].y + part[1][t].y) + (part[2][t].y + part[3][t].y);
        z.z = (part[0][t].z + part[1][t].z) + (part[2][t].z + part[3][t].z);
        z.w = (part[0][t].w + part[1][t].w) + (part[2][t].w + part[3][t].w);
        const int col = cg * 64 + t * 4;
        if (g == 0) {
            const float4 bf = *reinterpret_cast<const float4*>(b_f + col);
            const float4 cv = *reinterpret_cast<const float4*>(c0 + col);
            float4 r;
            r.x = cv.x / (1.f + expf(-(z.x + bf.x)));
            r.y = cv.y / (1.f + expf(-(z.y + bf.y)));
            r.z = cv.z / (1.f + expf(-(z.z + bf.z)));
            r.w = cv.w / (1.f + expf(-(z.w + bf.w)));
            *reinterpret_cast<float4*>(vbuf + col) = r;   // v = sig(zf)*c0
        } else {
            const float4 bo = *reinterpret_cast<const float4*>(b_o + col);
            float4 r;
            r.x = 1.f / (1.f + expf(-(z.x + bo.x)));
            r.y = 1.f / (1.f + expf(-(z.y + bo.y)));
            r.z = 1.f / (1.f + expf(-(z.z + bo.z)));
            r.w = 1.f / (1.f + expf(-(z.w + bo.w)));
            *reinterpret_cast<float4*>(obuf + col) = r;   // o gate
        }
    }
    __syncthreads();

    // ---- last-block ticket (device scope; robust to any initial cnt) ----
    if (t == 0) {
        __threadfence();                          // release vbuf/obuf writes
        const unsigned old = atomicInc(cnt, NBLK2 - 1u);
        lastFlag = (old == NBLK2 - 2u);           // exactly one block per call
    }
    __syncthreads();
    if (!lastFlag) return;
    __threadfence();                              // acquire

    // ---- finalize: h = o * tanh((v - mean) / (std_ddof1 + 1e-5)) ----
    const int lane = t & 63;
    const int wv   = t >> 6;
    __shared__ float red[2][4];

    float v[8], og[8];
    float lsum = 0.f;
#pragma unroll
    for (int e = 0; e < 8; ++e) {
        const int j = t * 8 + e;
        v[e]  = vbuf[j];
        og[e] = obuf[j];
        lsum += v[e];
    }
#pragma unroll
    for (int s = 32; s > 0; s >>= 1) lsum += __shfl_down(lsum, s);
    if (lane == 0) red[0][wv] = lsum;
    __syncthreads();
    const float mean = (red[0][0] + red[0][1] + red[0][2] + red[0][3]) * (1.f / 2048.f);

    float lss = 0.f;
#pragma unroll
    for (int e = 0; e < 8; ++e) {
        const float d = v[e] - mean;
        lss += d * d;
    }
#pragma unroll
    for (int s = 32; s > 0; s >>= 1) lss += __shfl_down(lss, s);
    if (lane == 0) red[1][wv] = lss;
    __syncthreads();
    const float var = (red[1][0] + red[1][1] + red[1][2] + red[1][3]) * (1.f / 2047.f);
    const float inv = 1.f / (sqrtf(var) + 1e-5f);

#pragma unroll
    for (int e = 0; e < 8; ++e) {
        const int j = t * 8 + e;
        out[j] = og[e] * tanhf((v[e] - mean) * inv);
    }
}

extern "C" void kernel_launch(void* const* d_in, const int* in_sizes, int n_in,
                              void* d_out, int out_size, void* d_ws, size_t ws_size,
                              hipStream_t stream) {
    // setup_inputs order:
    // 0:x 1:w_xi 2:w_xf 3:w_xo 4:w_xc 5:w_hi 6:w_hf 7:w_ho 8:w_hc
    // 9:b_i 10:b_f 11:b_o 12:b_c 13:h0 14:c0
    const float* x    = (const float*)d_in[0];
    const float* w_xf = (const float*)d_in[2];
    const float* w_xo = (const float*)d_in[3];
    const float* w_hf = (const float*)d_in[6];
    const float* w_ho = (const float*)d_in[7];
    const float* b_f  = (const float*)d_in[10];
    const float* b_o  = (const float*)d_in[11];
    const float* h0   = (const float*)d_in[13];
    const float* c0   = (const float*)d_in[14];
    float* out = (float*)d_out;

    float* zp     = (float*)d_ws;                  // [1024][1024] fp32 = 4 MB
    float* vbuf   = zp + (size_t)NBLK1 * 1024;     // 2048 fp32
    float* obuf   = vbuf + HS;                     // 2048 fp32
    unsigned* cnt = (unsigned*)(obuf + HS);        // ticket (any init ok)

    gemv_slab<<<NBLK1, 256, 0, stream>>>(x, h0, w_xf, w_hf, w_xo, w_ho, zp);
    reduce_fin<<<NBLK2, 256, 0, stream>>>(zp, b_f, b_o, c0, out, vbuf, obuf, cnt);
}